// Round 1
// baseline (470.834 us; speedup 1.0000x reference)
//
#include <hip/hip_runtime.h>
#include <stdint.h>

// Problem: B=2, S=2048, D=1024, H=16, dh=64
// Inputs fp32, OUTPUT fp32. Internals bf16 (threshold has bf16 floor).
#define SEQ    2048
#define DMODEL 1024

typedef __bf16 bf16x8 __attribute__((ext_vector_type(8)));
typedef float  f32x4  __attribute__((ext_vector_type(4)));

typedef __attribute__((address_space(1))) const void CGV;  // global
typedef __attribute__((address_space(3))) void LDSV;       // LDS

__device__ __forceinline__ void load_lds16(const void* g, void* l) {
    __builtin_amdgcn_global_load_lds((CGV*)g, (LDSV*)l, 16, 0, 0);
}

// ---------------------------------------------------------------------------
// Transpose+convert: in f32 [R][C] -> out bf16 [C][R].  grid (C/32, R/32), 256 thr
// ---------------------------------------------------------------------------
__global__ __launch_bounds__(256)
void transpose_f32_to_bf16(const float* __restrict__ in, __bf16* __restrict__ out,
                           int R, int C)
{
    __shared__ float tile[32][33];
    const int t  = threadIdx.x;
    const int tx = t & 31, ty = t >> 5;          // ty 0..7
    const int c0 = blockIdx.x * 32;
    const int r0 = blockIdx.y * 32;
#pragma unroll
    for (int i = 0; i < 4; ++i)
        tile[ty + i * 8][tx] = in[(size_t)(r0 + ty + i * 8) * C + c0 + tx];
    __syncthreads();
#pragma unroll
    for (int i = 0; i < 4; ++i)
        out[(size_t)(c0 + ty + i * 8) * R + r0 + tx] = (__bf16)tile[tx][ty + i * 8];
}

// ---------------------------------------------------------------------------
// V transpose (bf16): in [32][2048][64] -> out [32][64][2048]
// grid (SEQ/32, 64/32, 32), 256 thr
// ---------------------------------------------------------------------------
__global__ __launch_bounds__(256)
void transpose_v(const __bf16* __restrict__ in, __bf16* __restrict__ out)
{
    __shared__ __bf16 tile[32][34];
    const int t  = threadIdx.x;
    const int tx = t & 31, ty = t >> 5;
    const int s0 = blockIdx.x * 32;
    const int d0 = blockIdx.y * 32;
    const int bh = blockIdx.z;
    const __bf16* ip = in  + (size_t)bh * SEQ * 64;
    __bf16*       op = out + (size_t)bh * 64 * SEQ;
#pragma unroll
    for (int i = 0; i < 4; ++i)
        tile[ty + i * 8][tx] = ip[(size_t)(s0 + ty + i * 8) * 64 + d0 + tx];
    __syncthreads();
#pragma unroll
    for (int i = 0; i < 4; ++i)
        op[(size_t)(d0 + ty + i * 8) * SEQ + s0 + tx] = tile[tx][ty + i * 8];
}

// ---------------------------------------------------------------------------
// GEMM (m97 structure): C[M x N] = A[M x K] @ Bt[N x K]^T + bias[N]
//   Bt: bf16, pre-transposed weights. A: fp32 (convert path) or bf16
//   (global_load_lds path). Unpadded LDS tiles (wave-uniform-base constraint).
// mode 0: scatter bf16 into Q/K/V [B,H,S,dh];  mode 1: fp32 row-major store.
// ---------------------------------------------------------------------------
template<bool A_IS_F32>
__global__ __launch_bounds__(256)
void gemm_kernel(const void* __restrict__ Av, const __bf16* __restrict__ Bt,
                 const float* __restrict__ bias,
                 __bf16* __restrict__ Cq, __bf16* __restrict__ Ck,
                 __bf16* __restrict__ Cv, float* __restrict__ Cplain,
                 int K, int N, int mode)
{
    __shared__ __attribute__((aligned(16))) __bf16 As[128][32];
    __shared__ __attribute__((aligned(16))) __bf16 Bs[128][32];

    const int t    = threadIdx.x;
    const int wave = __builtin_amdgcn_readfirstlane(t >> 6);
    const int lane = t & 63;
    const int l15  = lane & 15;
    const int quad = lane >> 4;
    const int wm   = (wave >> 1) * 64;
    const int wn   = (wave & 1) * 64;
    const int m0   = blockIdx.y * 128;
    const int n0   = blockIdx.x * 128;

    const int arow  = lane >> 2;        // 0..15 within a 16-row slab
    const int akoff = (lane & 3) * 8;   // lane covers 8 bf16 of k

    f32x4 acc[4][4] = {};

    for (int k0 = 0; k0 < K; k0 += 32) {
        __syncthreads();
        // ---- stage A 128x32 ----
        if (A_IS_F32) {
            const float* A = (const float*)Av;
            int row = t >> 1, kk = (t & 1) * 16;
            const float* srcp = A + (size_t)(m0 + row) * K + k0 + kk;
            float4 v0 = *(const float4*)(srcp);
            float4 v1 = *(const float4*)(srcp + 4);
            float4 v2 = *(const float4*)(srcp + 8);
            float4 v3 = *(const float4*)(srcp + 12);
            __bf16 tmp[16] = {
                (__bf16)v0.x, (__bf16)v0.y, (__bf16)v0.z, (__bf16)v0.w,
                (__bf16)v1.x, (__bf16)v1.y, (__bf16)v1.z, (__bf16)v1.w,
                (__bf16)v2.x, (__bf16)v2.y, (__bf16)v2.z, (__bf16)v2.w,
                (__bf16)v3.x, (__bf16)v3.y, (__bf16)v3.z, (__bf16)v3.w };
            *(uint4*)(&As[row][kk])     = *(uint4*)(tmp);
            *(uint4*)(&As[row][kk + 8]) = *(uint4*)(tmp + 8);
        } else {
            const __bf16* A = (const __bf16*)Av;
#pragma unroll
            for (int p = 0; p < 2; ++p) {
                int slab = (wave * 2 + p) * 16;
                const __bf16* g = A + (size_t)(m0 + slab + arow) * K + k0 + akoff;
                load_lds16(g, &As[slab][0]);   // HW: base + lane*16
            }
        }
        // ---- stage B 128x32 via global_load_lds (Bt is [N][K] bf16) ----
#pragma unroll
        for (int p = 0; p < 2; ++p) {
            int slab = (wave * 2 + p) * 16;
            const __bf16* g = Bt + (size_t)(n0 + slab + arow) * K + k0 + akoff;
            load_lds16(g, &Bs[slab][0]);
        }
        __syncthreads();   // drains vmcnt (global_load_lds) + lgkm

        bf16x8 af[4], bfr[4];
#pragma unroll
        for (int mi = 0; mi < 4; ++mi)
            af[mi] = *(const bf16x8*)(&As[wm + mi * 16 + l15][quad * 8]);
#pragma unroll
        for (int ni = 0; ni < 4; ++ni)
            bfr[ni] = *(const bf16x8*)(&Bs[wn + ni * 16 + l15][quad * 8]);
#pragma unroll
        for (int mi = 0; mi < 4; ++mi)
#pragma unroll
            for (int ni = 0; ni < 4; ++ni)
                acc[mi][ni] = __builtin_amdgcn_mfma_f32_16x16x32_bf16(
                    af[mi], bfr[ni], acc[mi][ni], 0, 0, 0);
    }

    // epilogue: C/D layout col=lane&15, row=quad*4+reg
#pragma unroll
    for (int mi = 0; mi < 4; ++mi) {
        int rowb = m0 + wm + mi * 16 + quad * 4;
#pragma unroll
        for (int ni = 0; ni < 4; ++ni) {
            int col = n0 + wn + ni * 16 + l15;
            float bia = bias[col];
#pragma unroll
            for (int r = 0; r < 4; ++r) {
                float v = acc[mi][ni][r] + bia;
                int rr = rowb + r;
                if (mode == 0) {
                    int b = rr >> 11;
                    int s = rr & 2047;
                    int part = col >> 10;
                    int rem  = col & 1023;
                    int h = rem >> 6;
                    int d = rem & 63;
                    __bf16* dst = (part == 0) ? Cq : (part == 1) ? Ck : Cv;
                    dst[(((size_t)(b * 16 + h)) * SEQ + s) * 64 + d] = (__bf16)v;
                } else {
                    Cplain[(size_t)rr * N + col] = v;   // fp32 output
                }
            }
        }
    }
}

// ---------------------------------------------------------------------------
// MFMA flash attention, v2: barrier-free, S^T layout.
//   - QK^T computed SWAPPED: mfma(kf, qf) -> S^T[key][q]; key on (quad,r),
//     q on l15. Mask loads become float4 (keys contiguous per lane).
//   - softmax: lane-local 16-value reduce + shfl_xor(16,32); SCALAR m/l state.
//   - P written to LDS already transposed (A-fragment layout), packed 8B
//     stores (2-way bank aliasing = free). Ps is PER-WAVE -> no __syncthreads
//     anywhere; wave-internal lgkmcnt(0) + sched_barrier orders write->read.
//   - V read directly from global (L2-resident: 256KB/head shared by 32
//     blocks); fragments prefetched to regs under the softmax VALU phase.
// grid (B*H=32, S/64=32); 4 waves, each wave owns 16 q rows.
// ---------------------------------------------------------------------------
__global__ __launch_bounds__(256, 4)
void attn_kernel(const __bf16* __restrict__ Q, const __bf16* __restrict__ Kb,
                 const __bf16* __restrict__ Vtg, const float* __restrict__ mask,
                 __bf16* __restrict__ Out)
{
    __shared__ __attribute__((aligned(16))) __bf16 Ps[4][16][72];  // per-wave P [q][key]

    const int t    = threadIdx.x;
    const int wave = t >> 6;
    const int lane = t & 63;
    const int l15  = lane & 15;
    const int quad = lane >> 4;
    const int bh   = blockIdx.x;
    const int b    = bh >> 4;
    const int h    = bh & 15;
    const int q0   = blockIdx.y * 64 + wave * 16;

    const __bf16* Qp  = Q   + (size_t)bh * SEQ * 64;
    const __bf16* Kp  = Kb  + (size_t)bh * SEQ * 64;
    const __bf16* Vtp = Vtg + (size_t)bh * 64 * SEQ;   // [d][s]
    // mask row for THIS lane's q (= q0+l15), 4-key chunk base at quad*4
    const float*  Mp  = mask + (size_t)b * SEQ * SEQ + (size_t)(q0 + l15) * SEQ + quad * 4;

    bf16x8 qf[2];
#pragma unroll
    for (int ks = 0; ks < 2; ++ks)
        qf[ks] = *(const bf16x8*)(Qp + (size_t)(q0 + l15) * 64 + ks * 32 + quad * 8);

    f32x4 oacc[4] = {};
    float mrun = -1e30f, lrun = 0.f;   // scalar state: this lane's q = q0+l15

    for (int kt = 0; kt < SEQ / 64; ++kt) {
        const int key0 = kt * 64;

        // 1. mask loads (independent; latency hides under QK MFMAs)
        float4 mk[4];
#pragma unroll
        for (int nb = 0; nb < 4; ++nb)
            mk[nb] = *(const float4*)(Mp + key0 + nb * 16);

        // 2. S^T = K Q^T : sa[nb][r] = S[key0+nb*16+quad*4+r][q0+l15]
        f32x4 sa[4];
#pragma unroll
        for (int nb = 0; nb < 4; ++nb) {
            f32x4 z = {};
            const __bf16* kp = Kp + (size_t)(key0 + nb * 16 + l15) * 64 + quad * 8;
            bf16x8 kf0 = *(const bf16x8*)(kp);
            bf16x8 kf1 = *(const bf16x8*)(kp + 32);
            z = __builtin_amdgcn_mfma_f32_16x16x32_bf16(kf0, qf[0], z, 0, 0, 0);
            z = __builtin_amdgcn_mfma_f32_16x16x32_bf16(kf1, qf[1], z, 0, 0, 0);
            sa[nb] = z;
        }

        // 3. prefetch V fragments to regs (latency hides under softmax VALU)
        bf16x8 vf[4][2];
#pragma unroll
        for (int cb = 0; cb < 4; ++cb)
#pragma unroll
            for (int ks = 0; ks < 2; ++ks)
                vf[cb][ks] = *(const bf16x8*)(Vtp + (size_t)(cb * 16 + l15) * SEQ
                                              + key0 + ks * 32 + quad * 8);

        // 4. mask+scale:  s = m*(0.125*sa + 1e4) - 1e4  (== sa*0.125*m + (m-1)*1e4)
        float s[4][4];
#pragma unroll
        for (int nb = 0; nb < 4; ++nb)
#pragma unroll
            for (int r = 0; r < 4; ++r) {
                float m = ((const float*)&mk[nb])[r];
                float tt = __fmaf_rn(0.125f, sa[nb][r], 10000.0f);
                s[nb][r] = __fmaf_rn(m, tt, -10000.0f);
            }

        // 5. online softmax for q=l15 (lane-local over 16 keys, then quads)
        float vmax = fmaxf(fmaxf(s[0][0], s[0][1]), fmaxf(s[0][2], s[0][3]));
#pragma unroll
        for (int nb = 1; nb < 4; ++nb)
            vmax = fmaxf(vmax, fmaxf(fmaxf(s[nb][0], s[nb][1]),
                                     fmaxf(s[nb][2], s[nb][3])));
        vmax = fmaxf(vmax, __shfl_xor(vmax, 16));
        vmax = fmaxf(vmax, __shfl_xor(vmax, 32));
        float mnew  = fmaxf(mrun, vmax);
        float alpha = __expf(mrun - mnew);
        mrun = mnew;

        float accs = 0.f;
#pragma unroll
        for (int nb = 0; nb < 4; ++nb)
#pragma unroll
            for (int r = 0; r < 4; ++r) {
                float p = __expf(s[nb][r] - mnew);
                s[nb][r] = p;
                accs += p;
            }
        accs += __shfl_xor(accs, 16);
        accs += __shfl_xor(accs, 32);
        lrun = lrun * alpha + accs;

        // 6. write P (already [q][key] layout): 4x packed 8B stores
#pragma unroll
        for (int nb = 0; nb < 4; ++nb) {
            union { __bf16 hh[4]; uint2 u; } pk;
            pk.hh[0] = (__bf16)s[nb][0];
            pk.hh[1] = (__bf16)s[nb][1];
            pk.hh[2] = (__bf16)s[nb][2];
            pk.hh[3] = (__bf16)s[nb][3];
            *(uint2*)(&Ps[wave][l15][nb * 16 + quad * 4]) = pk.u;
        }

        // wave-internal ordering: all lanes' P stores complete before reads
        asm volatile("s_waitcnt lgkmcnt(0)" ::: "memory");
        __builtin_amdgcn_sched_barrier(0);

        // 7. broadcast alpha to O rows (row q = quad*4+r lives in lane l15=q)
        float a4[4];
#pragma unroll
        for (int r = 0; r < 4; ++r)
            a4[r] = __shfl(alpha, quad * 4 + r);
#pragma unroll
        for (int cb = 0; cb < 4; ++cb)
#pragma unroll
            for (int r = 0; r < 4; ++r)
                oacc[cb][r] *= a4[r];

        bf16x8 pf[2];
#pragma unroll
        for (int ks = 0; ks < 2; ++ks)
            pf[ks] = *(const bf16x8*)(&Ps[wave][l15][ks * 32 + quad * 8]);

        // 8. O += P V  (pure-register MFMA cluster)
        __builtin_amdgcn_s_setprio(1);
#pragma unroll
        for (int cb = 0; cb < 4; ++cb)
#pragma unroll
            for (int ks = 0; ks < 2; ++ks)
                oacc[cb] = __builtin_amdgcn_mfma_f32_16x16x32_bf16(
                    pf[ks], vf[cb][ks], oacc[cb], 0, 0, 0);
        __builtin_amdgcn_s_setprio(0);
    }

    // epilogue (bf16 Ao, feeds GEMM2's global_load_lds A path)
    float l4[4];
#pragma unroll
    for (int r = 0; r < 4; ++r)
        l4[r] = __shfl(lrun, quad * 4 + r);
#pragma unroll
    for (int cb = 0; cb < 4; ++cb) {
#pragma unroll
        for (int r = 0; r < 4; ++r) {
            int qq = q0 + quad * 4 + r;
            float v = oacc[cb][r] / l4[r];
            Out[((size_t)(b * SEQ + qq)) * DMODEL + h * 64 + cb * 16 + l15] = (__bf16)v;
        }
    }
}

// ---------------------------------------------------------------------------
extern "C" void kernel_launch(void* const* d_in, const int* in_sizes, int n_in,
                              void* d_out, int out_size, void* d_ws, size_t ws_size,
                              hipStream_t stream)
{
    const float* src  = nullptr;  // 4194304
    const float* mask = nullptr;  // 8388608
    const float* Wqkv = nullptr;  // 3145728
    const float* bqkv = nullptr;  // 3072
    const float* Wout = nullptr;  // 1048576
    const float* bout = nullptr;  // 1024
    for (int i = 0; i < n_in; ++i) {
        switch (in_sizes[i]) {
            case 4194304: src  = (const float*)d_in[i]; break;
            case 8388608: mask = (const float*)d_in[i]; break;
            case 3145728: Wqkv = (const float*)d_in[i]; break;
            case 3072:    bqkv = (const float*)d_in[i]; break;
            case 1048576: Wout = (const float*)d_in[i]; break;
            case 1024:    bout = (const float*)d_in[i]; break;
        }
    }
    float* out = (float*)d_out;                  // [2,2048,1024] fp32

    const size_t NE = (size_t)2 * 16 * SEQ * 64; // 4M elems
    __bf16* Qb     = (__bf16*)d_ws;              // 4M
    __bf16* Kb     = Qb + NE;                    // 4M
    __bf16* Vb     = Kb + NE;                    // 4M (dead after transpose_v)
    __bf16* Vtg    = Vb + NE;                    // 4M
    __bf16* Wqkv_t = Vtg + NE;                   // 3M  [3072][1024]
    __bf16* Wout_t = Wqkv_t + (size_t)3072 * 1024; // 1M [1024][1024]
    __bf16* Ao     = Vb;                         // alias: Vb dead by then
    // total: 4+4+4+4+3+1 = 20M bf16 = 40MB

    // weight transposes (bf16 convert)
    transpose_f32_to_bf16<<<dim3(3072 / 32, 1024 / 32), 256, 0, stream>>>(
        Wqkv, Wqkv_t, 1024, 3072);
    transpose_f32_to_bf16<<<dim3(1024 / 32, 1024 / 32), 256, 0, stream>>>(
        Wout, Wout_t, 1024, 1024);

    // GEMM1: src(f32) @ Wqkv -> scatter Q/K/V
    gemm_kernel<true><<<dim3(3072 / 128, 4096 / 128), 256, 0, stream>>>(
        (const void*)src, Wqkv_t, bqkv, Qb, Kb, Vb, nullptr, 1024, 3072, 0);

    // V -> V^T
    transpose_v<<<dim3(SEQ / 32, 2, 32), 256, 0, stream>>>(Vb, Vtg);

    // attention
    attn_kernel<<<dim3(32, SEQ / 64), 256, 0, stream>>>(Qb, Kb, Vtg, mask, Ao);

    // GEMM2: Ao(bf16) @ Wout + b -> out (fp32)
    gemm_kernel<false><<<dim3(1024 / 128, 4096 / 128), 256, 0, stream>>>(
        (const void*)Ao, Wout_t, bout, nullptr, nullptr, nullptr, out, 1024, 1024, 1);
}

// Round 2
// 448.799 us; speedup vs baseline: 1.0491x; 1.0491x over previous
//
#include <hip/hip_runtime.h>
#include <stdint.h>

// Problem: B=2, S=2048, D=1024, H=16, dh=64
// Inputs fp32, OUTPUT fp32. Internals bf16 (threshold has bf16 floor).
#define SEQ    2048
#define DMODEL 1024

typedef __bf16 bf16x8 __attribute__((ext_vector_type(8)));
typedef float  f32x4  __attribute__((ext_vector_type(4)));

typedef __attribute__((address_space(1))) const void CGV;  // global
typedef __attribute__((address_space(3))) void LDSV;       // LDS

__device__ __forceinline__ void load_lds16(const void* g, void* l) {
    __builtin_amdgcn_global_load_lds((CGV*)g, (LDSV*)l, 16, 0, 0);
}

// ---------------------------------------------------------------------------
// Transpose+convert: in f32 [R][C] -> out bf16 [C][R].  grid (C/32, R/32), 256 thr
// ---------------------------------------------------------------------------
__global__ __launch_bounds__(256)
void transpose_f32_to_bf16(const float* __restrict__ in, __bf16* __restrict__ out,
                           int R, int C)
{
    __shared__ float tile[32][33];
    const int t  = threadIdx.x;
    const int tx = t & 31, ty = t >> 5;          // ty 0..7
    const int c0 = blockIdx.x * 32;
    const int r0 = blockIdx.y * 32;
#pragma unroll
    for (int i = 0; i < 4; ++i)
        tile[ty + i * 8][tx] = in[(size_t)(r0 + ty + i * 8) * C + c0 + tx];
    __syncthreads();
#pragma unroll
    for (int i = 0; i < 4; ++i)
        out[(size_t)(c0 + ty + i * 8) * R + r0 + tx] = (__bf16)tile[tx][ty + i * 8];
}

// ---------------------------------------------------------------------------
// V transpose (bf16): in [32][2048][64] -> out [32][64][2048]
// grid (SEQ/32, 64/32, 32), 256 thr
// ---------------------------------------------------------------------------
__global__ __launch_bounds__(256)
void transpose_v(const __bf16* __restrict__ in, __bf16* __restrict__ out)
{
    __shared__ __bf16 tile[32][34];
    const int t  = threadIdx.x;
    const int tx = t & 31, ty = t >> 5;
    const int s0 = blockIdx.x * 32;
    const int d0 = blockIdx.y * 32;
    const int bh = blockIdx.z;
    const __bf16* ip = in  + (size_t)bh * SEQ * 64;
    __bf16*       op = out + (size_t)bh * 64 * SEQ;
#pragma unroll
    for (int i = 0; i < 4; ++i)
        tile[ty + i * 8][tx] = ip[(size_t)(s0 + ty + i * 8) * 64 + d0 + tx];
    __syncthreads();
#pragma unroll
    for (int i = 0; i < 4; ++i)
        op[(size_t)(d0 + ty + i * 8) * SEQ + s0 + tx] = tile[tx][ty + i * 8];
}

// ---------------------------------------------------------------------------
// GEMM (m97 structure): C[M x N] = A[M x K] @ Bt[N x K]^T + bias[N]
// ---------------------------------------------------------------------------
template<bool A_IS_F32>
__global__ __launch_bounds__(256)
void gemm_kernel(const void* __restrict__ Av, const __bf16* __restrict__ Bt,
                 const float* __restrict__ bias,
                 __bf16* __restrict__ Cq, __bf16* __restrict__ Ck,
                 __bf16* __restrict__ Cv, float* __restrict__ Cplain,
                 int K, int N, int mode)
{
    __shared__ __attribute__((aligned(16))) __bf16 As[128][32];
    __shared__ __attribute__((aligned(16))) __bf16 Bs[128][32];

    const int t    = threadIdx.x;
    const int wave = __builtin_amdgcn_readfirstlane(t >> 6);
    const int lane = t & 63;
    const int l15  = lane & 15;
    const int quad = lane >> 4;
    const int wm   = (wave >> 1) * 64;
    const int wn   = (wave & 1) * 64;
    const int m0   = blockIdx.y * 128;
    const int n0   = blockIdx.x * 128;

    const int arow  = lane >> 2;        // 0..15 within a 16-row slab
    const int akoff = (lane & 3) * 8;   // lane covers 8 bf16 of k

    f32x4 acc[4][4] = {};

    for (int k0 = 0; k0 < K; k0 += 32) {
        __syncthreads();
        // ---- stage A 128x32 ----
        if (A_IS_F32) {
            const float* A = (const float*)Av;
            int row = t >> 1, kk = (t & 1) * 16;
            const float* srcp = A + (size_t)(m0 + row) * K + k0 + kk;
            float4 v0 = *(const float4*)(srcp);
            float4 v1 = *(const float4*)(srcp + 4);
            float4 v2 = *(const float4*)(srcp + 8);
            float4 v3 = *(const float4*)(srcp + 12);
            __bf16 tmp[16] = {
                (__bf16)v0.x, (__bf16)v0.y, (__bf16)v0.z, (__bf16)v0.w,
                (__bf16)v1.x, (__bf16)v1.y, (__bf16)v1.z, (__bf16)v1.w,
                (__bf16)v2.x, (__bf16)v2.y, (__bf16)v2.z, (__bf16)v2.w,
                (__bf16)v3.x, (__bf16)v3.y, (__bf16)v3.z, (__bf16)v3.w };
            *(uint4*)(&As[row][kk])     = *(uint4*)(tmp);
            *(uint4*)(&As[row][kk + 8]) = *(uint4*)(tmp + 8);
        } else {
            const __bf16* A = (const __bf16*)Av;
#pragma unroll
            for (int p = 0; p < 2; ++p) {
                int slab = (wave * 2 + p) * 16;
                const __bf16* g = A + (size_t)(m0 + slab + arow) * K + k0 + akoff;
                load_lds16(g, &As[slab][0]);   // HW: base + lane*16
            }
        }
        // ---- stage B 128x32 via global_load_lds (Bt is [N][K] bf16) ----
#pragma unroll
        for (int p = 0; p < 2; ++p) {
            int slab = (wave * 2 + p) * 16;
            const __bf16* g = Bt + (size_t)(n0 + slab + arow) * K + k0 + akoff;
            load_lds16(g, &Bs[slab][0]);
        }
        __syncthreads();   // drains vmcnt (global_load_lds) + lgkm

        bf16x8 af[4], bfr[4];
#pragma unroll
        for (int mi = 0; mi < 4; ++mi)
            af[mi] = *(const bf16x8*)(&As[wm + mi * 16 + l15][quad * 8]);
#pragma unroll
        for (int ni = 0; ni < 4; ++ni)
            bfr[ni] = *(const bf16x8*)(&Bs[wn + ni * 16 + l15][quad * 8]);
#pragma unroll
        for (int mi = 0; mi < 4; ++mi)
#pragma unroll
            for (int ni = 0; ni < 4; ++ni)
                acc[mi][ni] = __builtin_amdgcn_mfma_f32_16x16x32_bf16(
                    af[mi], bfr[ni], acc[mi][ni], 0, 0, 0);
    }

    // epilogue: C/D layout col=lane&15, row=quad*4+reg
#pragma unroll
    for (int mi = 0; mi < 4; ++mi) {
        int rowb = m0 + wm + mi * 16 + quad * 4;
#pragma unroll
        for (int ni = 0; ni < 4; ++ni) {
            int col = n0 + wn + ni * 16 + l15;
            float bia = bias[col];
#pragma unroll
            for (int r = 0; r < 4; ++r) {
                float v = acc[mi][ni][r] + bia;
                int rr = rowb + r;
                if (mode == 0) {
                    int b = rr >> 11;
                    int s = rr & 2047;
                    int part = col >> 10;
                    int rem  = col & 1023;
                    int h = rem >> 6;
                    int d = rem & 63;
                    __bf16* dst = (part == 0) ? Cq : (part == 1) ? Ck : Cv;
                    dst[(((size_t)(b * 16 + h)) * SEQ + s) * 64 + d] = (__bf16)v;
                } else {
                    Cplain[(size_t)rr * N + col] = v;   // fp32 output
                }
            }
        }
    }
}

// ---------------------------------------------------------------------------
// MFMA flash attention v3 = v1 structure + async double-buffered V staging.
//   - V staged via global_load_lds (sink-proof async) into LDS double buffer;
//     LDS layout linear [64][128B-rows], SOURCE pre-swizzled with
//     byte ^= ((d&7)<<4) so PV ds_read_b128 hits the 8-cycle bank floor.
//   - mask prefetched one tile ahead into regs (issued early, drained at the
//     single end-of-tile barrier after ~full-tile compute has covered latency).
//   - K fragment loads issued FIRST each tile (vmcnt is in-order FIFO: QK's
//     wait must not cover the later HBM mask prefetches). sched_barrier(0)
//     fences pin issue order.
//   - Ps write->read sync is wave-local (Ps[wave] private): lgkmcnt(0) fence
//     instead of block barrier. ONE __syncthreads per tile (publishes next V).
//   - s_setprio(1) around PV MFMA cluster.
// grid (B*H=32, S/64=32); 4 waves, each wave owns 16 q rows.
// ---------------------------------------------------------------------------
__device__ __forceinline__ void stage_v(const __bf16* __restrict__ Vtp,
                                        __bf16* buf, int wave, int lane, int key0)
{
    // chunk c = wave*2+p covers d rows [c*8, c*8+8), 1KB linear LDS.
    // lane L writes LDS bytes [c*1024 + L*16, +16) = row d=c*8+(L>>3),
    // in-row 16B slot (L&7).  Source swizzle: logical keys 8*((L&7)^(L>>3)).
#pragma unroll
    for (int p = 0; p < 2; ++p) {
        int c   = wave * 2 + p;
        int d   = c * 8 + (lane >> 3);
        int ksl = ((lane & 7) ^ (lane >> 3)) * 8;
        load_lds16(Vtp + (size_t)d * SEQ + key0 + ksl, buf + c * 512);
    }
}

__device__ __forceinline__ void prefetch_mask(float (&mk)[4][4],
                                              const float* __restrict__ Mbase,
                                              const int (&moff)[4], int key)
{
#pragma unroll
    for (int r = 0; r < 4; ++r)
#pragma unroll
        for (int nb = 0; nb < 4; ++nb)
            mk[r][nb] = Mbase[(size_t)(moff[r] + key + nb * 16)];
}

__device__ __forceinline__ void attn_tile(
    f32x4 (&oacc)[4], float (&mrun)[4], float (&lrun)[4],
    const bf16x8 (&qf)[2], const float (&mk)[4][4], float (&mknext)[4][4],
    const __bf16* __restrict__ Kp, int key0, int keyn,
    const __bf16* __restrict__ Vtp,
    const __bf16* VbufCur, __bf16* VbufNext,
    const float* __restrict__ Mbase, const int (&moff)[4],
    __bf16* Psw, int wave, int lane, int l15, int quad)
{
    // --- 1. K fragment loads: FIRST in the vmcnt FIFO ---
    bf16x8 kf[4][2];
#pragma unroll
    for (int nb = 0; nb < 4; ++nb) {
        const __bf16* kp = Kp + (size_t)(key0 + nb * 16 + l15) * 64 + quad * 8;
        kf[nb][0] = *(const bf16x8*)(kp);
        kf[nb][1] = *(const bf16x8*)(kp + 32);
    }
    __builtin_amdgcn_sched_barrier(0);

    // --- 2. async prefetch of NEXT tile: V -> other LDS buf, mask -> regs ---
    stage_v(Vtp, VbufNext, wave, lane, keyn);
    prefetch_mask(mknext, Mbase, moff, keyn);
    __builtin_amdgcn_sched_barrier(0);

    // --- 3. S = Q K^T ---
    f32x4 sa[4];
#pragma unroll
    for (int nb = 0; nb < 4; ++nb) {
        f32x4 z = {};
        z = __builtin_amdgcn_mfma_f32_16x16x32_bf16(qf[0], kf[nb][0], z, 0, 0, 0);
        z = __builtin_amdgcn_mfma_f32_16x16x32_bf16(qf[1], kf[nb][1], z, 0, 0, 0);
        sa[nb] = z;
    }

    // --- 4. mask + scale ---
    float s[4][4];
#pragma unroll
    for (int nb = 0; nb < 4; ++nb)
#pragma unroll
        for (int r = 0; r < 4; ++r) {
            float m = mk[r][nb];
            s[nb][r] = sa[nb][r] * 0.125f * m + (m - 1.0f) * 10000.0f;
        }

    // --- 5. online softmax (rows on (quad,r), keys across l15) ---
    float alpha[4];
#pragma unroll
    for (int r = 0; r < 4; ++r) {
        float v = fmaxf(fmaxf(s[0][r], s[1][r]), fmaxf(s[2][r], s[3][r]));
        v = fmaxf(v, __shfl_xor(v, 1));
        v = fmaxf(v, __shfl_xor(v, 2));
        v = fmaxf(v, __shfl_xor(v, 4));
        v = fmaxf(v, __shfl_xor(v, 8));
        float mnew = fmaxf(mrun[r], v);
        alpha[r] = __expf(mrun[r] - mnew);
        mrun[r] = mnew;
    }
#pragma unroll
    for (int r = 0; r < 4; ++r) {
        float accs = 0.f;
#pragma unroll
        for (int nb = 0; nb < 4; ++nb) {
            float p = __expf(s[nb][r] - mrun[r]);
            s[nb][r] = p;
            accs += p;
        }
        accs += __shfl_xor(accs, 1);
        accs += __shfl_xor(accs, 2);
        accs += __shfl_xor(accs, 4);
        accs += __shfl_xor(accs, 8);
        lrun[r] = lrun[r] * alpha[r] + accs;
    }

    // --- 6. P: C-layout -> LDS (wave-private) ---
#pragma unroll
    for (int nb = 0; nb < 4; ++nb)
#pragma unroll
        for (int r = 0; r < 4; ++r)
            Psw[(quad * 4 + r) * 72 + nb * 16 + l15] = (__bf16)s[nb][r];
    // wave-local: all 64 lanes' ds_writes complete before cross-lane ds_reads
    asm volatile("s_waitcnt lgkmcnt(0)" ::: "memory");
    __builtin_amdgcn_sched_barrier(0);

    // --- 7. O = O*alpha + P V ---
#pragma unroll
    for (int cb = 0; cb < 4; ++cb)
#pragma unroll
        for (int r = 0; r < 4; ++r)
            oacc[cb][r] *= alpha[r];

    bf16x8 pf[2];
#pragma unroll
    for (int ks = 0; ks < 2; ++ks)
        pf[ks] = *(const bf16x8*)(Psw + l15 * 72 + ks * 32 + quad * 8);

    const char* vb = (const char*)VbufCur;
    __builtin_amdgcn_s_setprio(1);
#pragma unroll
    for (int cb = 0; cb < 4; ++cb) {
#pragma unroll
        for (int ks = 0; ks < 2; ++ks) {
            // logical (d=cb*16+l15, k=ks*32+quad*8); byte = d*128 + (2k ^ ((d&7)<<4))
            bf16x8 vf = *(const bf16x8*)(vb + (cb * 16 + l15) * 128 +
                               ((ks * 64 + quad * 16) ^ ((l15 & 7) << 4)));
            oacc[cb] = __builtin_amdgcn_mfma_f32_16x16x32_bf16(pf[ks], vf, oacc[cb], 0, 0, 0);
        }
    }
    __builtin_amdgcn_s_setprio(0);
}

__global__ __launch_bounds__(256, 4)
void attn_kernel(const __bf16* __restrict__ Q, const __bf16* __restrict__ Kb,
                 const __bf16* __restrict__ Vtg, const float* __restrict__ mask,
                 __bf16* __restrict__ Out)
{
    __shared__ __attribute__((aligned(16))) __bf16 Vb[2][64 * 64];   // linear, swizzled content
    __shared__ __attribute__((aligned(16))) __bf16 Ps[4][16][72];    // per-wave P

    const int t    = threadIdx.x;
    const int wave = __builtin_amdgcn_readfirstlane(t >> 6);
    const int lane = t & 63;
    const int l15  = lane & 15;
    const int quad = lane >> 4;
    const int bh   = blockIdx.x;
    const int b    = bh >> 4;
    const int h    = bh & 15;
    const int q0   = blockIdx.y * 64 + wave * 16;

    const __bf16* Qp  = Q   + (size_t)bh * SEQ * 64;
    const __bf16* Kp  = Kb  + (size_t)bh * SEQ * 64;
    const __bf16* Vtp = Vtg + (size_t)bh * 64 * SEQ;   // [d][s]
    const float*  Mbase = mask + (size_t)b * SEQ * SEQ + (size_t)q0 * SEQ;

    int moff[4];
#pragma unroll
    for (int r = 0; r < 4; ++r) moff[r] = (quad * 4 + r) * SEQ + l15;

    bf16x8 qf[2];
#pragma unroll
    for (int ks = 0; ks < 2; ++ks)
        qf[ks] = *(const bf16x8*)(Qp + (size_t)(q0 + l15) * 64 + ks * 32 + quad * 8);

    f32x4 oacc[4] = {};
    float mrun[4], lrun[4];
#pragma unroll
    for (int r = 0; r < 4; ++r) { mrun[r] = -1e30f; lrun[r] = 0.f; }

    float mkA[4][4], mkB[4][4];
    __bf16* Psw = &Ps[wave][0][0];

    // prologue: stage tile 0 (V -> buf0, mask -> mkA)
    stage_v(Vtp, &Vb[0][0], wave, lane, 0);
    prefetch_mask(mkA, Mbase, moff, 0);
    __syncthreads();   // drains vmcnt: buf0 + mkA ready

    for (int kt = 0; kt < SEQ / 64; kt += 2) {
        const int k0 = kt * 64;
        const int k1 = k0 + 64;
        int k2 = k1 + 64; if (k2 > SEQ - 64) k2 = SEQ - 64;   // clamp (last prefetch redundant)

        // even tile: compute buf0/mkA, prefetch -> buf1/mkB
        attn_tile(oacc, mrun, lrun, qf, mkA, mkB, Kp, k0, k1,
                  Vtp, &Vb[0][0], &Vb[1][0], Mbase, moff, Psw, wave, lane, l15, quad);
        __syncthreads();   // publish buf1 (+ mkB drained)

        // odd tile: compute buf1/mkB, prefetch -> buf0/mkA
        attn_tile(oacc, mrun, lrun, qf, mkB, mkA, Kp, k1, k2,
                  Vtp, &Vb[1][0], &Vb[0][0], Mbase, moff, Psw, wave, lane, l15, quad);
        __syncthreads();   // publish buf0 (+ mkA drained)
    }

    // epilogue (bf16 Ao, feeds GEMM2's global_load_lds A path)
#pragma unroll
    for (int cb = 0; cb < 4; ++cb) {
#pragma unroll
        for (int r = 0; r < 4; ++r) {
            int qq = q0 + quad * 4 + r;
            float v = oacc[cb][r] / lrun[r];
            Out[((size_t)(b * SEQ + qq)) * DMODEL + h * 64 + cb * 16 + l15] = (__bf16)v;
        }
    }
}

// ---------------------------------------------------------------------------
extern "C" void kernel_launch(void* const* d_in, const int* in_sizes, int n_in,
                              void* d_out, int out_size, void* d_ws, size_t ws_size,
                              hipStream_t stream)
{
    const float* src  = nullptr;  // 4194304
    const float* mask = nullptr;  // 8388608
    const float* Wqkv = nullptr;  // 3145728
    const float* bqkv = nullptr;  // 3072
    const float* Wout = nullptr;  // 1048576
    const float* bout = nullptr;  // 1024
    for (int i = 0; i < n_in; ++i) {
        switch (in_sizes[i]) {
            case 4194304: src  = (const float*)d_in[i]; break;
            case 8388608: mask = (const float*)d_in[i]; break;
            case 3145728: Wqkv = (const float*)d_in[i]; break;
            case 3072:    bqkv = (const float*)d_in[i]; break;
            case 1048576: Wout = (const float*)d_in[i]; break;
            case 1024:    bout = (const float*)d_in[i]; break;
        }
    }
    float* out = (float*)d_out;                  // [2,2048,1024] fp32

    const size_t NE = (size_t)2 * 16 * SEQ * 64; // 4M elems
    __bf16* Qb     = (__bf16*)d_ws;              // 4M
    __bf16* Kb     = Qb + NE;                    // 4M
    __bf16* Vb     = Kb + NE;                    // 4M (dead after transpose_v)
    __bf16* Vtg    = Vb + NE;                    // 4M
    __bf16* Wqkv_t = Vtg + NE;                   // 3M  [3072][1024]
    __bf16* Wout_t = Wqkv_t + (size_t)3072 * 1024; // 1M [1024][1024]
    __bf16* Ao     = Vb;                         // alias: Vb dead by then
    // total: 4+4+4+4+3+1 = 20M bf16 = 40MB

    // weight transposes (bf16 convert)
    transpose_f32_to_bf16<<<dim3(3072 / 32, 1024 / 32), 256, 0, stream>>>(
        Wqkv, Wqkv_t, 1024, 3072);
    transpose_f32_to_bf16<<<dim3(1024 / 32, 1024 / 32), 256, 0, stream>>>(
        Wout, Wout_t, 1024, 1024);

    // GEMM1: src(f32) @ Wqkv -> scatter Q/K/V
    gemm_kernel<true><<<dim3(3072 / 128, 4096 / 128), 256, 0, stream>>>(
        (const void*)src, Wqkv_t, bqkv, Qb, Kb, Vb, nullptr, 1024, 3072, 0);

    // V -> V^T
    transpose_v<<<dim3(SEQ / 32, 2, 32), 256, 0, stream>>>(Vb, Vtg);

    // attention
    attn_kernel<<<dim3(32, SEQ / 64), 256, 0, stream>>>(Qb, Kb, Vtg, mask, Ao);

    // GEMM2: Ao(bf16) @ Wout + b -> out (fp32)
    gemm_kernel<false><<<dim3(1024 / 128, 4096 / 128), 256, 0, stream>>>(
        (const void*)Ao, Wout_t, bout, nullptr, nullptr, nullptr, out, 1024, 1024, 1);
}

// Round 3
// 370.930 us; speedup vs baseline: 1.2693x; 1.2099x over previous
//
#include <hip/hip_runtime.h>
#include <stdint.h>

// Problem: B=2, S=2048, D=1024, H=16, dh=64
// Inputs fp32, OUTPUT fp32. Internals bf16 (threshold has bf16 floor).
#define SEQ    2048
#define DMODEL 1024

typedef __bf16 bf16x8 __attribute__((ext_vector_type(8)));
typedef float  f32x4  __attribute__((ext_vector_type(4)));

typedef __attribute__((address_space(1))) const void CGV;  // global
typedef __attribute__((address_space(3))) void LDSV;       // LDS

__device__ __forceinline__ void load_lds16(const void* g, void* l) {
    __builtin_amdgcn_global_load_lds((CGV*)g, (LDSV*)l, 16, 0, 0);
}

// ---------------------------------------------------------------------------
// Transpose+convert: in f32 [R][C] -> out bf16 [C][R].  grid (C/32, R/32), 256 thr
// ---------------------------------------------------------------------------
__global__ __launch_bounds__(256)
void transpose_f32_to_bf16(const float* __restrict__ in, __bf16* __restrict__ out,
                           int R, int C)
{
    __shared__ float tile[32][33];
    const int t  = threadIdx.x;
    const int tx = t & 31, ty = t >> 5;          // ty 0..7
    const int c0 = blockIdx.x * 32;
    const int r0 = blockIdx.y * 32;
#pragma unroll
    for (int i = 0; i < 4; ++i)
        tile[ty + i * 8][tx] = in[(size_t)(r0 + ty + i * 8) * C + c0 + tx];
    __syncthreads();
#pragma unroll
    for (int i = 0; i < 4; ++i)
        out[(size_t)(c0 + ty + i * 8) * R + r0 + tx] = (__bf16)tile[tx][ty + i * 8];
}

// ---------------------------------------------------------------------------
// V transpose (bf16): in [32][2048][64] -> out [32][64][2048]
// grid (SEQ/32, 64/32, 32), 256 thr
// ---------------------------------------------------------------------------
__global__ __launch_bounds__(256)
void transpose_v(const __bf16* __restrict__ in, __bf16* __restrict__ out)
{
    __shared__ __bf16 tile[32][34];
    const int t  = threadIdx.x;
    const int tx = t & 31, ty = t >> 5;
    const int s0 = blockIdx.x * 32;
    const int d0 = blockIdx.y * 32;
    const int bh = blockIdx.z;
    const __bf16* ip = in  + (size_t)bh * SEQ * 64;
    __bf16*       op = out + (size_t)bh * 64 * SEQ;
#pragma unroll
    for (int i = 0; i < 4; ++i)
        tile[ty + i * 8][tx] = ip[(size_t)(s0 + ty + i * 8) * 64 + d0 + tx];
    __syncthreads();
#pragma unroll
    for (int i = 0; i < 4; ++i)
        op[(size_t)(d0 + ty + i * 8) * SEQ + s0 + tx] = tile[tx][ty + i * 8];
}

// ---------------------------------------------------------------------------
// GEMM (m97 structure): C[M x N] = A[M x K] @ Bt[N x K]^T + bias[N]
// ---------------------------------------------------------------------------
template<bool A_IS_F32>
__global__ __launch_bounds__(256)
void gemm_kernel(const void* __restrict__ Av, const __bf16* __restrict__ Bt,
                 const float* __restrict__ bias,
                 __bf16* __restrict__ Cq, __bf16* __restrict__ Ck,
                 __bf16* __restrict__ Cv, float* __restrict__ Cplain,
                 int K, int N, int mode)
{
    __shared__ __attribute__((aligned(16))) __bf16 As[128][32];
    __shared__ __attribute__((aligned(16))) __bf16 Bs[128][32];

    const int t    = threadIdx.x;
    const int wave = __builtin_amdgcn_readfirstlane(t >> 6);
    const int lane = t & 63;
    const int l15  = lane & 15;
    const int quad = lane >> 4;
    const int wm   = (wave >> 1) * 64;
    const int wn   = (wave & 1) * 64;
    const int m0   = blockIdx.y * 128;
    const int n0   = blockIdx.x * 128;

    const int arow  = lane >> 2;        // 0..15 within a 16-row slab
    const int akoff = (lane & 3) * 8;   // lane covers 8 bf16 of k

    f32x4 acc[4][4] = {};

    for (int k0 = 0; k0 < K; k0 += 32) {
        __syncthreads();
        // ---- stage A 128x32 ----
        if (A_IS_F32) {
            const float* A = (const float*)Av;
            int row = t >> 1, kk = (t & 1) * 16;
            const float* srcp = A + (size_t)(m0 + row) * K + k0 + kk;
            float4 v0 = *(const float4*)(srcp);
            float4 v1 = *(const float4*)(srcp + 4);
            float4 v2 = *(const float4*)(srcp + 8);
            float4 v3 = *(const float4*)(srcp + 12);
            __bf16 tmp[16] = {
                (__bf16)v0.x, (__bf16)v0.y, (__bf16)v0.z, (__bf16)v0.w,
                (__bf16)v1.x, (__bf16)v1.y, (__bf16)v1.z, (__bf16)v1.w,
                (__bf16)v2.x, (__bf16)v2.y, (__bf16)v2.z, (__bf16)v2.w,
                (__bf16)v3.x, (__bf16)v3.y, (__bf16)v3.z, (__bf16)v3.w };
            *(uint4*)(&As[row][kk])     = *(uint4*)(tmp);
            *(uint4*)(&As[row][kk + 8]) = *(uint4*)(tmp + 8);
        } else {
            const __bf16* A = (const __bf16*)Av;
#pragma unroll
            for (int p = 0; p < 2; ++p) {
                int slab = (wave * 2 + p) * 16;
                const __bf16* g = A + (size_t)(m0 + slab + arow) * K + k0 + akoff;
                load_lds16(g, &As[slab][0]);   // HW: base + lane*16
            }
        }
        // ---- stage B 128x32 via global_load_lds (Bt is [N][K] bf16) ----
#pragma unroll
        for (int p = 0; p < 2; ++p) {
            int slab = (wave * 2 + p) * 16;
            const __bf16* g = Bt + (size_t)(n0 + slab + arow) * K + k0 + akoff;
            load_lds16(g, &Bs[slab][0]);
        }
        __syncthreads();   // drains vmcnt (global_load_lds) + lgkm

        bf16x8 af[4], bfr[4];
#pragma unroll
        for (int mi = 0; mi < 4; ++mi)
            af[mi] = *(const bf16x8*)(&As[wm + mi * 16 + l15][quad * 8]);
#pragma unroll
        for (int ni = 0; ni < 4; ++ni)
            bfr[ni] = *(const bf16x8*)(&Bs[wn + ni * 16 + l15][quad * 8]);
#pragma unroll
        for (int mi = 0; mi < 4; ++mi)
#pragma unroll
            for (int ni = 0; ni < 4; ++ni)
                acc[mi][ni] = __builtin_amdgcn_mfma_f32_16x16x32_bf16(
                    af[mi], bfr[ni], acc[mi][ni], 0, 0, 0);
    }

    // epilogue: C/D layout col=lane&15, row=quad*4+reg
#pragma unroll
    for (int mi = 0; mi < 4; ++mi) {
        int rowb = m0 + wm + mi * 16 + quad * 4;
#pragma unroll
        for (int ni = 0; ni < 4; ++ni) {
            int col = n0 + wn + ni * 16 + l15;
            float bia = bias[col];
#pragma unroll
            for (int r = 0; r < 4; ++r) {
                float v = acc[mi][ni][r] + bia;
                int rr = rowb + r;
                if (mode == 0) {
                    int b = rr >> 11;
                    int s = rr & 2047;
                    int part = col >> 10;
                    int rem  = col & 1023;
                    int h = rem >> 6;
                    int d = rem & 63;
                    __bf16* dst = (part == 0) ? Cq : (part == 1) ? Ck : Cv;
                    dst[(((size_t)(b * 16 + h)) * SEQ + s) * 64 + d] = (__bf16)v;
                } else {
                    Cplain[(size_t)rr * N + col] = v;   // fp32 output
                }
            }
        }
    }
}

// ---------------------------------------------------------------------------
// MFMA flash attention v4: S^T orientation (v2-verified math), KVBLK=128,
// monolithic body (no helper calls -> no scratch-backed locals, v3 lesson).
//   - QK swapped: sa[nb] = mfma(kf, qf) -> S^T[key][q]; q on l15, key on
//     (nb, quad*4+r). Mask loads are f32x4; softmax is lane-local over 32
//     values + 2 shfl_xor; scalar m/l state. P written packed (8B) already
//     in A-fragment layout.
//   - V staged to LDS [64][136] (single buffer) with plain loads issued
//     right after QK; drained by the mid-tile barrier (~500cy cover).
//   - mask: ONE f32x4[8] register buffer. Consumed by the mask-FMA right
//     after QK, then immediately re-loaded with tile t+1's mask (cover =
//     softmax+PV+next QK). sched_barrier(0) fences pin issue order so the
//     QK kf waits never drain mask/stage FIFO entries.
//   - 2 barriers per 128 keys (v1 had 2 per 64). setprio(1) on PV cluster.
// grid (B*H=32, S/64=32); 4 waves, each wave owns 16 q rows.
// ---------------------------------------------------------------------------
__global__ __launch_bounds__(256, 4)
void attn_kernel(const __bf16* __restrict__ Q, const __bf16* __restrict__ Kb,
                 const __bf16* __restrict__ Vtg, const float* __restrict__ mask,
                 __bf16* __restrict__ Out)
{
    __shared__ __attribute__((aligned(16))) __bf16 Vt[64][136];     // [d][key], pad->2-way banks
    __shared__ __attribute__((aligned(16))) __bf16 Ps[4][16][136];  // per-wave P [q][key]

    const int t    = threadIdx.x;
    const int wave = __builtin_amdgcn_readfirstlane(t >> 6);
    const int lane = t & 63;
    const int l15  = lane & 15;
    const int quad = lane >> 4;
    const int bh   = blockIdx.x;
    const int b    = bh >> 4;
    const int h    = bh & 15;
    const int q0   = blockIdx.y * 64 + wave * 16;

    const __bf16* Qp  = Q   + (size_t)bh * SEQ * 64;
    const __bf16* Kp  = Kb  + (size_t)bh * SEQ * 64;
    const __bf16* Vtp = Vtg + (size_t)bh * 64 * SEQ;   // [d][s]
    // mask row for THIS lane's q (= q0+l15); 4-key chunk base at quad*4
    const float*  Mrow = mask + (size_t)b * SEQ * SEQ + (size_t)(q0 + l15) * SEQ + quad * 4;

    bf16x8 qf[2];
#pragma unroll
    for (int ks = 0; ks < 2; ++ks)
        qf[ks] = *(const bf16x8*)(Qp + (size_t)(q0 + l15) * 64 + ks * 32 + quad * 8);

    f32x4 oacc[4] = {};
    float mrun = -1e30f, lrun = 0.f;   // scalar state: this lane's q = q0+l15

    // prologue: mask for tile 0
    f32x4 mk[8];
#pragma unroll
    for (int nb = 0; nb < 8; ++nb)
        mk[nb] = *(const f32x4*)(Mrow + nb * 16);

    for (int kt = 0; kt < SEQ / 128; ++kt) {
        const int key0 = kt * 128;
        const int keyn = (key0 + 128 < SEQ) ? key0 + 128 : key0;  // clamp (last reload harmless)

        // --- 1. QK: kf loads first in the vmcnt FIFO ---
        f32x4 sa[8];
#pragma unroll
        for (int nb = 0; nb < 8; ++nb) {
            const __bf16* kp = Kp + (size_t)(key0 + nb * 16 + l15) * 64 + quad * 8;
            bf16x8 kf0 = *(const bf16x8*)(kp);
            bf16x8 kf1 = *(const bf16x8*)(kp + 32);
            f32x4 z = {};
            z = __builtin_amdgcn_mfma_f32_16x16x32_bf16(kf0, qf[0], z, 0, 0, 0);
            z = __builtin_amdgcn_mfma_f32_16x16x32_bf16(kf1, qf[1], z, 0, 0, 0);
            sa[nb] = z;
        }
        __builtin_amdgcn_sched_barrier(0);

        // --- 2. stage V(kt) -> LDS (drained at mid-tile barrier) ---
#pragma unroll
        for (int i = 0; i < 4; ++i) {
            int c  = t + i * 256;          // chunk 0..1023
            int d  = c >> 4;               // 0..63
            int ko = (c & 15) * 8;         // key offset 0..120
            *(uint4*)(&Vt[d][ko]) =
                *(const uint4*)(Vtp + (size_t)d * SEQ + key0 + ko);
        }
        __builtin_amdgcn_sched_barrier(0);

        // --- 3. mask + scale (consume mk; frees the buffer) ---
#pragma unroll
        for (int nb = 0; nb < 8; ++nb)
#pragma unroll
            for (int r = 0; r < 4; ++r) {
                float m  = mk[nb][r];
                float tt = __fmaf_rn(0.125f, sa[nb][r], 10000.0f);
                sa[nb][r] = __fmaf_rn(m, tt, -10000.0f);
            }
        __builtin_amdgcn_sched_barrier(0);

        // --- 4. prefetch mask(kt+1) into the SAME buffer ---
#pragma unroll
        for (int nb = 0; nb < 8; ++nb)
            mk[nb] = *(const f32x4*)(Mrow + keyn + nb * 16);
        __builtin_amdgcn_sched_barrier(0);

        // --- 5. online softmax for q=l15 (lane-local 32 keys, then quads) ---
        float vmax = -1e30f;
#pragma unroll
        for (int nb = 0; nb < 8; ++nb)
#pragma unroll
            for (int r = 0; r < 4; ++r)
                vmax = fmaxf(vmax, sa[nb][r]);
        vmax = fmaxf(vmax, __shfl_xor(vmax, 16));
        vmax = fmaxf(vmax, __shfl_xor(vmax, 32));
        float mnew  = fmaxf(mrun, vmax);
        float alpha = __expf(mrun - mnew);
        mrun = mnew;

        float accs = 0.f;
#pragma unroll
        for (int nb = 0; nb < 8; ++nb)
#pragma unroll
            for (int r = 0; r < 4; ++r) {
                float p = __expf(sa[nb][r] - mnew);
                sa[nb][r] = p;
                accs += p;
            }
        accs += __shfl_xor(accs, 16);
        accs += __shfl_xor(accs, 32);
        lrun = lrun * alpha + accs;

        // --- 6. pack P -> Ps (already [q][key] A-layout): 8 packed 8B stores ---
#pragma unroll
        for (int nb = 0; nb < 8; ++nb) {
            union { __bf16 hh[4]; uint2 u; } pk;
            pk.hh[0] = (__bf16)sa[nb][0];
            pk.hh[1] = (__bf16)sa[nb][1];
            pk.hh[2] = (__bf16)sa[nb][2];
            pk.hh[3] = (__bf16)sa[nb][3];
            *(uint2*)(&Ps[wave][l15][nb * 16 + quad * 4]) = pk.u;
        }

        __syncthreads();   // V(kt) staged + Ps visible (drains vmcnt+lgkm)

        // --- 7. alpha broadcast + rescale O ---
        float a4[4];
#pragma unroll
        for (int r = 0; r < 4; ++r)
            a4[r] = __shfl(alpha, quad * 4 + r);
#pragma unroll
        for (int cb = 0; cb < 4; ++cb)
#pragma unroll
            for (int r = 0; r < 4; ++r)
                oacc[cb][r] *= a4[r];

        bf16x8 pf[4];
#pragma unroll
        for (int ks = 0; ks < 4; ++ks)
            pf[ks] = *(const bf16x8*)(&Ps[wave][l15][ks * 32 + quad * 8]);

        // --- 8. O += P V (pure LDS/reg MFMA cluster) ---
        __builtin_amdgcn_s_setprio(1);
#pragma unroll
        for (int cb = 0; cb < 4; ++cb)
#pragma unroll
            for (int ks = 0; ks < 4; ++ks) {
                bf16x8 vf = *(const bf16x8*)(&Vt[cb * 16 + l15][ks * 32 + quad * 8]);
                oacc[cb] = __builtin_amdgcn_mfma_f32_16x16x32_bf16(
                    pf[ks], vf, oacc[cb], 0, 0, 0);
            }
        __builtin_amdgcn_s_setprio(0);

        __syncthreads();   // PV reads done -> next iteration may overwrite Vt
    }

    // epilogue (v2-verified): l broadcast, bf16 Ao out
    float l4[4];
#pragma unroll
    for (int r = 0; r < 4; ++r)
        l4[r] = __shfl(lrun, quad * 4 + r);
#pragma unroll
    for (int cb = 0; cb < 4; ++cb) {
#pragma unroll
        for (int r = 0; r < 4; ++r) {
            int qq = q0 + quad * 4 + r;
            float v = oacc[cb][r] / l4[r];
            Out[((size_t)(b * SEQ + qq)) * DMODEL + h * 64 + cb * 16 + l15] = (__bf16)v;
        }
    }
}

// ---------------------------------------------------------------------------
extern "C" void kernel_launch(void* const* d_in, const int* in_sizes, int n_in,
                              void* d_out, int out_size, void* d_ws, size_t ws_size,
                              hipStream_t stream)
{
    const float* src  = nullptr;  // 4194304
    const float* mask = nullptr;  // 8388608
    const float* Wqkv = nullptr;  // 3145728
    const float* bqkv = nullptr;  // 3072
    const float* Wout = nullptr;  // 1048576
    const float* bout = nullptr;  // 1024
    for (int i = 0; i < n_in; ++i) {
        switch (in_sizes[i]) {
            case 4194304: src  = (const float*)d_in[i]; break;
            case 8388608: mask = (const float*)d_in[i]; break;
            case 3145728: Wqkv = (const float*)d_in[i]; break;
            case 3072:    bqkv = (const float*)d_in[i]; break;
            case 1048576: Wout = (const float*)d_in[i]; break;
            case 1024:    bout = (const float*)d_in[i]; break;
        }
    }
    float* out = (float*)d_out;                  // [2,2048,1024] fp32

    const size_t NE = (size_t)2 * 16 * SEQ * 64; // 4M elems
    __bf16* Qb     = (__bf16*)d_ws;              // 4M
    __bf16* Kb     = Qb + NE;                    // 4M
    __bf16* Vb     = Kb + NE;                    // 4M (dead after transpose_v)
    __bf16* Vtg    = Vb + NE;                    // 4M
    __bf16* Wqkv_t = Vtg + NE;                   // 3M  [3072][1024]
    __bf16* Wout_t = Wqkv_t + (size_t)3072 * 1024; // 1M [1024][1024]
    __bf16* Ao     = Vb;                         // alias: Vb dead by then
    // total: 4+4+4+4+3+1 = 20M bf16 = 40MB

    // weight transposes (bf16 convert)
    transpose_f32_to_bf16<<<dim3(3072 / 32, 1024 / 32), 256, 0, stream>>>(
        Wqkv, Wqkv_t, 1024, 3072);
    transpose_f32_to_bf16<<<dim3(1024 / 32, 1024 / 32), 256, 0, stream>>>(
        Wout, Wout_t, 1024, 1024);

    // GEMM1: src(f32) @ Wqkv -> scatter Q/K/V
    gemm_kernel<true><<<dim3(3072 / 128, 4096 / 128), 256, 0, stream>>>(
        (const void*)src, Wqkv_t, bqkv, Qb, Kb, Vb, nullptr, 1024, 3072, 0);

    // V -> V^T
    transpose_v<<<dim3(SEQ / 32, 2, 32), 256, 0, stream>>>(Vb, Vtg);

    // attention
    attn_kernel<<<dim3(32, SEQ / 64), 256, 0, stream>>>(Qb, Kb, Vtg, mask, Ao);

    // GEMM2: Ao(bf16) @ Wout + b -> out (fp32)
    gemm_kernel<false><<<dim3(1024 / 128, 4096 / 128), 256, 0, stream>>>(
        (const void*)Ao, Wout_t, bout, nullptr, nullptr, nullptr, out, 1024, 1024, 1);
}

// Round 4
// 262.873 us; speedup vs baseline: 1.7911x; 1.4111x over previous
//
#include <hip/hip_runtime.h>
#include <stdint.h>

// Problem: B=2, S=2048, D=1024, H=16, dh=64
// Inputs fp32, OUTPUT fp32. Internals bf16 (threshold has bf16 floor).
#define SEQ    2048
#define DMODEL 1024

typedef __bf16 bf16x8 __attribute__((ext_vector_type(8)));
typedef float  f32x4  __attribute__((ext_vector_type(4)));

typedef __attribute__((address_space(1))) const void CGV;  // global
typedef __attribute__((address_space(3))) void LDSV;       // LDS

__device__ __forceinline__ void load_lds16(const void* g, void* l) {
    __builtin_amdgcn_global_load_lds((CGV*)g, (LDSV*)l, 16, 0, 0);
}

// ---------------------------------------------------------------------------
// Transpose+convert: in f32 [R][C] -> out bf16 [C][R].  grid (C/32, R/32), 256 thr
// ---------------------------------------------------------------------------
__global__ __launch_bounds__(256)
void transpose_f32_to_bf16(const float* __restrict__ in, __bf16* __restrict__ out,
                           int R, int C)
{
    __shared__ float tile[32][33];
    const int t  = threadIdx.x;
    const int tx = t & 31, ty = t >> 5;          // ty 0..7
    const int c0 = blockIdx.x * 32;
    const int r0 = blockIdx.y * 32;
#pragma unroll
    for (int i = 0; i < 4; ++i)
        tile[ty + i * 8][tx] = in[(size_t)(r0 + ty + i * 8) * C + c0 + tx];
    __syncthreads();
#pragma unroll
    for (int i = 0; i < 4; ++i)
        out[(size_t)(c0 + ty + i * 8) * R + r0 + tx] = (__bf16)tile[tx][ty + i * 8];
}

// ---------------------------------------------------------------------------
// f32 -> bf16 convert (vectorized). grid n/(256*8), 256 thr
// ---------------------------------------------------------------------------
__global__ __launch_bounds__(256)
void convert_f32_to_bf16(const float* __restrict__ in, __bf16* __restrict__ out)
{
    const int i = (blockIdx.x * 256 + threadIdx.x) * 8;
    float4 a = *(const float4*)(in + i);
    float4 b = *(const float4*)(in + i + 4);
    __bf16 tmp[8] = { (__bf16)a.x, (__bf16)a.y, (__bf16)a.z, (__bf16)a.w,
                      (__bf16)b.x, (__bf16)b.y, (__bf16)b.z, (__bf16)b.w };
    *(uint4*)(out + i) = *(uint4*)tmp;
}

// ---------------------------------------------------------------------------
// V transpose (bf16): in [32][2048][64] -> out [32][64][2048]
// grid (SEQ/32, 64/32, 32), 256 thr
// ---------------------------------------------------------------------------
__global__ __launch_bounds__(256)
void transpose_v(const __bf16* __restrict__ in, __bf16* __restrict__ out)
{
    __shared__ __bf16 tile[32][34];
    const int t  = threadIdx.x;
    const int tx = t & 31, ty = t >> 5;
    const int s0 = blockIdx.x * 32;
    const int d0 = blockIdx.y * 32;
    const int bh = blockIdx.z;
    const __bf16* ip = in  + (size_t)bh * SEQ * 64;
    __bf16*       op = out + (size_t)bh * 64 * SEQ;
#pragma unroll
    for (int i = 0; i < 4; ++i)
        tile[ty + i * 8][tx] = ip[(size_t)(s0 + ty + i * 8) * 64 + d0 + tx];
    __syncthreads();
#pragma unroll
    for (int i = 0; i < 4; ++i)
        op[(size_t)(d0 + ty + i * 8) * SEQ + s0 + tx] = tile[tx][ty + i * 8];
}

// ---------------------------------------------------------------------------
// GEMM (m97 structure): C[M x N] = A[M x K] @ Bt[N x K]^T + bias[N]
// ---------------------------------------------------------------------------
template<bool A_IS_F32>
__global__ __launch_bounds__(256)
void gemm_kernel(const void* __restrict__ Av, const __bf16* __restrict__ Bt,
                 const float* __restrict__ bias,
                 __bf16* __restrict__ Cq, __bf16* __restrict__ Ck,
                 __bf16* __restrict__ Cv, float* __restrict__ Cplain,
                 int K, int N, int mode)
{
    __shared__ __attribute__((aligned(16))) __bf16 As[128][32];
    __shared__ __attribute__((aligned(16))) __bf16 Bs[128][32];

    const int t    = threadIdx.x;
    const int wave = __builtin_amdgcn_readfirstlane(t >> 6);
    const int lane = t & 63;
    const int l15  = lane & 15;
    const int quad = lane >> 4;
    const int wm   = (wave >> 1) * 64;
    const int wn   = (wave & 1) * 64;
    const int m0   = blockIdx.y * 128;
    const int n0   = blockIdx.x * 128;

    const int arow  = lane >> 2;        // 0..15 within a 16-row slab
    const int akoff = (lane & 3) * 8;   // lane covers 8 bf16 of k

    f32x4 acc[4][4] = {};

    for (int k0 = 0; k0 < K; k0 += 32) {
        __syncthreads();
        // ---- stage A 128x32 ----
        if (A_IS_F32) {
            const float* A = (const float*)Av;
            int row = t >> 1, kk = (t & 1) * 16;
            const float* srcp = A + (size_t)(m0 + row) * K + k0 + kk;
            float4 v0 = *(const float4*)(srcp);
            float4 v1 = *(const float4*)(srcp + 4);
            float4 v2 = *(const float4*)(srcp + 8);
            float4 v3 = *(const float4*)(srcp + 12);
            __bf16 tmp[16] = {
                (__bf16)v0.x, (__bf16)v0.y, (__bf16)v0.z, (__bf16)v0.w,
                (__bf16)v1.x, (__bf16)v1.y, (__bf16)v1.z, (__bf16)v1.w,
                (__bf16)v2.x, (__bf16)v2.y, (__bf16)v2.z, (__bf16)v2.w,
                (__bf16)v3.x, (__bf16)v3.y, (__bf16)v3.z, (__bf16)v3.w };
            *(uint4*)(&As[row][kk])     = *(uint4*)(tmp);
            *(uint4*)(&As[row][kk + 8]) = *(uint4*)(tmp + 8);
        } else {
            const __bf16* A = (const __bf16*)Av;
#pragma unroll
            for (int p = 0; p < 2; ++p) {
                int slab = (wave * 2 + p) * 16;
                const __bf16* g = A + (size_t)(m0 + slab + arow) * K + k0 + akoff;
                load_lds16(g, &As[slab][0]);   // HW: base + lane*16
            }
        }
        // ---- stage B 128x32 via global_load_lds (Bt is [N][K] bf16) ----
#pragma unroll
        for (int p = 0; p < 2; ++p) {
            int slab = (wave * 2 + p) * 16;
            const __bf16* g = Bt + (size_t)(n0 + slab + arow) * K + k0 + akoff;
            load_lds16(g, &Bs[slab][0]);
        }
        __syncthreads();   // drains vmcnt (global_load_lds) + lgkm

        bf16x8 af[4], bfr[4];
#pragma unroll
        for (int mi = 0; mi < 4; ++mi)
            af[mi] = *(const bf16x8*)(&As[wm + mi * 16 + l15][quad * 8]);
#pragma unroll
        for (int ni = 0; ni < 4; ++ni)
            bfr[ni] = *(const bf16x8*)(&Bs[wn + ni * 16 + l15][quad * 8]);
#pragma unroll
        for (int mi = 0; mi < 4; ++mi)
#pragma unroll
            for (int ni = 0; ni < 4; ++ni)
                acc[mi][ni] = __builtin_amdgcn_mfma_f32_16x16x32_bf16(
                    af[mi], bfr[ni], acc[mi][ni], 0, 0, 0);
    }

    // epilogue: C/D layout col=lane&15, row=quad*4+reg
#pragma unroll
    for (int mi = 0; mi < 4; ++mi) {
        int rowb = m0 + wm + mi * 16 + quad * 4;
#pragma unroll
        for (int ni = 0; ni < 4; ++ni) {
            int col = n0 + wn + ni * 16 + l15;
            float bia = bias[col];
#pragma unroll
            for (int r = 0; r < 4; ++r) {
                float v = acc[mi][ni][r] + bia;
                int rr = rowb + r;
                if (mode == 0) {
                    int b = rr >> 11;
                    int s = rr & 2047;
                    int part = col >> 10;
                    int rem  = col & 1023;
                    int h = rem >> 6;
                    int d = rem & 63;
                    __bf16* dst = (part == 0) ? Cq : (part == 1) ? Ck : Cv;
                    dst[(((size_t)(b * 16 + h)) * SEQ + s) * 64 + d] = (__bf16)v;
                } else {
                    Cplain[(size_t)rr * N + col] = v;   // fp32 output
                }
            }
        }
    }
}

// ---------------------------------------------------------------------------
// MFMA flash attention v5: pipelined K/V LDS double-buffer with counted waits.
//   - K AND V staged via global_load_lds one tile ahead (async, sink-proof).
//     LDS linear [row][64] per tile; source pre-swizzled slot^=(row&7), reads
//     apply the same XOR (v3-verified both-sides pattern, rule #21).
//   - ONE raw s_barrier per tile: vmcnt(0) right before it waits on loads
//     issued a full tile body earlier (~1000cy cover). No __syncthreads ->
//     no forced drain mid-tile.
//   - S^T softmax (v4-verified): q on l15, keys on (nb,quad,r); scalar m/l;
//     f32x4 mask loads, single register mask buffer, consume-then-prefetch
//     (loop-carried => cannot sink). P packed 8B into XOR-swizzled Ps.
//   - Ps sync wave-local (lgkmcnt(0)+sched_barrier, v1-verified).
//   - LDS = 16K (Kt dbuf) + 16K (Vt dbuf) + 8K (Ps) = 40960 B -> 4 blocks/CU.
// grid (B*H=32, S/64=32); 4 waves, each wave owns 16 q rows.
// ---------------------------------------------------------------------------
__global__ __launch_bounds__(256, 4)
void attn_kernel(const __bf16* __restrict__ Q, const __bf16* __restrict__ Kb,
                 const __bf16* __restrict__ Vtg, const float* __restrict__ mask,
                 __bf16* __restrict__ Out)
{
    __shared__ __attribute__((aligned(16))) __bf16 Kt[2][64 * 64]; // [key][d] swz
    __shared__ __attribute__((aligned(16))) __bf16 Vt[2][64 * 64]; // [d][key] swz
    __shared__ __attribute__((aligned(16))) __bf16 Ps[4][16 * 64]; // [q][key] swz

    const int t    = threadIdx.x;
    const int wave = __builtin_amdgcn_readfirstlane(t >> 6);
    const int lane = t & 63;
    const int l15  = lane & 15;
    const int quad = lane >> 4;
    const int swq  = lane & 7;                  // == l15 & 7
    const int bh   = blockIdx.x;
    const int b    = bh >> 4;
    const int h    = bh & 15;
    const int q0   = blockIdx.y * 64 + wave * 16;

    const __bf16* Qp  = Q   + (size_t)bh * SEQ * 64;
    const __bf16* Kp  = Kb  + (size_t)bh * SEQ * 64;
    const __bf16* Vtp = Vtg + (size_t)bh * 64 * SEQ;   // [d][s]
    const float*  Mrow = mask + (size_t)b * SEQ * SEQ + (size_t)(q0 + l15) * SEQ + quad * 4;

    // ---- stage-source lane constants (v3-verified swizzle family) ----
    // chunk c = wave*2+p covers rows [c*8, c*8+8); lane L -> row c*8+(L>>3),
    // LDS 16B slot (L&7); source slot = (L&7) ^ (L>>3)  (involution w/ row&7).
    const int ch  = wave * 2;
    const int rw0 = ch * 8 + (lane >> 3);
    const int swz = ((lane & 7) ^ (lane >> 3)) * 8;    // element offset
    const __bf16* kS0 = Kp  + (size_t)rw0 * 64 + swz;        // + keyn*64/tile
    const __bf16* kS1 = Kp  + (size_t)(rw0 + 8) * 64 + swz;
    const __bf16* vS0 = Vtp + (size_t)rw0 * SEQ + swz;       // + keyn/tile
    const __bf16* vS1 = Vtp + (size_t)(rw0 + 8) * SEQ + swz;

    bf16x8 qf[2];
#pragma unroll
    for (int ks = 0; ks < 2; ++ks)
        qf[ks] = *(const bf16x8*)(Qp + (size_t)(q0 + l15) * 64 + ks * 32 + quad * 8);

    f32x4 oacc[4] = {};
    float mrun = -1e30f, lrun = 0.f;   // scalar state: this lane's q = q0+l15

    // ---- prologue: stage tile 0 into buf0, mask tile 0 into regs ----
    load_lds16(kS0, &Kt[0][ch * 512]);
    load_lds16(kS1, &Kt[0][(ch + 1) * 512]);
    load_lds16(vS0, &Vt[0][ch * 512]);
    load_lds16(vS1, &Vt[0][(ch + 1) * 512]);
    f32x4 mk[4];
#pragma unroll
    for (int nb = 0; nb < 4; ++nb)
        mk[nb] = *(const f32x4*)(Mrow + nb * 16);

    const char* PsW = (const char*)&Ps[wave][0] + l15 * 128;

#pragma unroll 2
    for (int tt = 0; tt < SEQ / 64; ++tt) {
        const int key0 = tt * 64;
        const int keyn = (key0 + 64 <= SEQ - 64) ? key0 + 64 : SEQ - 64; // clamp
        const int cur  = tt & 1;
        const char* kcur = (const char*)&Kt[cur][0];
        const char* vcur = (const char*)&Vt[cur][0];
        __bf16* knxt = &Kt[cur ^ 1][0];
        __bf16* vnxt = &Vt[cur ^ 1][0];

        // --- top-of-tile: loads staged last tile are done; publish buffers ---
        asm volatile("s_waitcnt vmcnt(0)" ::: "memory");
        __builtin_amdgcn_s_barrier();
        __builtin_amdgcn_sched_barrier(0);

        // --- issue stage of tile t+1 (async; drained at NEXT tile's top) ---
        load_lds16(kS0 + (size_t)keyn * 64, knxt + ch * 512);
        load_lds16(kS1 + (size_t)keyn * 64, knxt + (ch + 1) * 512);
        load_lds16(vS0 + keyn, vnxt + ch * 512);
        load_lds16(vS1 + keyn, vnxt + (ch + 1) * 512);
        __builtin_amdgcn_sched_barrier(0);

        // --- QK from LDS K[cur] (S^T: rows=keys on l15, q via qf) ---
        f32x4 sa[4];
#pragma unroll
        for (int nb = 0; nb < 4; ++nb) {
            const char* kb = kcur + (nb * 16 + l15) * 128;
            bf16x8 kf0 = *(const bf16x8*)(kb + (((quad) ^ swq) << 4));
            bf16x8 kf1 = *(const bf16x8*)(kb + (((4 + quad) ^ swq) << 4));
            f32x4 z = {};
            z = __builtin_amdgcn_mfma_f32_16x16x32_bf16(kf0, qf[0], z, 0, 0, 0);
            z = __builtin_amdgcn_mfma_f32_16x16x32_bf16(kf1, qf[1], z, 0, 0, 0);
            sa[nb] = z;
        }

        // --- mask + scale (consume mk), then prefetch mask(t+1) same buffer ---
#pragma unroll
        for (int nb = 0; nb < 4; ++nb)
#pragma unroll
            for (int r = 0; r < 4; ++r) {
                float m  = mk[nb][r];
                float tt2 = __fmaf_rn(0.125f, sa[nb][r], 10000.0f);
                sa[nb][r] = __fmaf_rn(m, tt2, -10000.0f);
            }
#pragma unroll
        for (int nb = 0; nb < 4; ++nb)
            mk[nb] = *(const f32x4*)(Mrow + keyn + nb * 16);

        // --- online softmax for q = q0+l15 (16 lane-local keys, 2 shfl) ---
        float vmax = -1e30f;
#pragma unroll
        for (int nb = 0; nb < 4; ++nb)
#pragma unroll
            for (int r = 0; r < 4; ++r)
                vmax = fmaxf(vmax, sa[nb][r]);
        vmax = fmaxf(vmax, __shfl_xor(vmax, 16));
        vmax = fmaxf(vmax, __shfl_xor(vmax, 32));
        float mnew  = fmaxf(mrun, vmax);
        float alpha = __expf(mrun - mnew);
        mrun = mnew;

        float accs = 0.f;
#pragma unroll
        for (int nb = 0; nb < 4; ++nb)
#pragma unroll
            for (int r = 0; r < 4; ++r) {
                float p = __expf(sa[nb][r] - mnew);
                sa[nb][r] = p;
                accs += p;
            }
        accs += __shfl_xor(accs, 16);
        accs += __shfl_xor(accs, 32);
        lrun = lrun * alpha + accs;

        // --- pack P -> Ps (swizzled, wave-private): 4 x 8B stores ---
        // logical: row q=l15, keys nb*16+quad*4+r -> slot16 = nb*2+(quad>>1),
        // half = quad&1; physical slot = slot16 ^ swq.
#pragma unroll
        for (int nb = 0; nb < 4; ++nb) {
            union { __bf16 hh[4]; uint2 u; } pk;
            pk.hh[0] = (__bf16)sa[nb][0];
            pk.hh[1] = (__bf16)sa[nb][1];
            pk.hh[2] = (__bf16)sa[nb][2];
            pk.hh[3] = (__bf16)sa[nb][3];
            *(uint2*)(PsW + (((nb * 2 + (quad >> 1)) ^ swq) << 4) + (quad & 1) * 8) = pk.u;
        }
        asm volatile("s_waitcnt lgkmcnt(0)" ::: "memory");
        __builtin_amdgcn_sched_barrier(0);

        // --- rescale O (alpha lives at lane l15=q -> broadcast to (quad,r)) ---
        float a4[4];
#pragma unroll
        for (int r = 0; r < 4; ++r)
            a4[r] = __shfl(alpha, quad * 4 + r);
#pragma unroll
        for (int cb = 0; cb < 4; ++cb)
#pragma unroll
            for (int r = 0; r < 4; ++r)
                oacc[cb][r] *= a4[r];

        bf16x8 pf0 = *(const bf16x8*)(PsW + (((quad) ^ swq) << 4));
        bf16x8 pf1 = *(const bf16x8*)(PsW + (((4 + quad) ^ swq) << 4));

        // --- O += P V from LDS V[cur] ---
        __builtin_amdgcn_s_setprio(1);
#pragma unroll
        for (int cb = 0; cb < 4; ++cb) {
            const char* vb = vcur + (cb * 16 + l15) * 128;
            bf16x8 vf0 = *(const bf16x8*)(vb + (((quad) ^ swq) << 4));
            bf16x8 vf1 = *(const bf16x8*)(vb + (((4 + quad) ^ swq) << 4));
            oacc[cb] = __builtin_amdgcn_mfma_f32_16x16x32_bf16(pf0, vf0, oacc[cb], 0, 0, 0);
            oacc[cb] = __builtin_amdgcn_mfma_f32_16x16x32_bf16(pf1, vf1, oacc[cb], 0, 0, 0);
        }
        __builtin_amdgcn_s_setprio(0);
    }

    // epilogue (v2/v4-verified): l broadcast, bf16 Ao out
    float l4[4];
#pragma unroll
    for (int r = 0; r < 4; ++r)
        l4[r] = __shfl(lrun, quad * 4 + r);
#pragma unroll
    for (int cb = 0; cb < 4; ++cb) {
#pragma unroll
        for (int r = 0; r < 4; ++r) {
            int qq = q0 + quad * 4 + r;
            float v = oacc[cb][r] / l4[r];
            Out[((size_t)(b * SEQ + qq)) * DMODEL + h * 64 + cb * 16 + l15] = (__bf16)v;
        }
    }
}

// ---------------------------------------------------------------------------
extern "C" void kernel_launch(void* const* d_in, const int* in_sizes, int n_in,
                              void* d_out, int out_size, void* d_ws, size_t ws_size,
                              hipStream_t stream)
{
    const float* src  = nullptr;  // 4194304
    const float* mask = nullptr;  // 8388608
    const float* Wqkv = nullptr;  // 3145728
    const float* bqkv = nullptr;  // 3072
    const float* Wout = nullptr;  // 1048576
    const float* bout = nullptr;  // 1024
    for (int i = 0; i < n_in; ++i) {
        switch (in_sizes[i]) {
            case 4194304: src  = (const float*)d_in[i]; break;
            case 8388608: mask = (const float*)d_in[i]; break;
            case 3145728: Wqkv = (const float*)d_in[i]; break;
            case 3072:    bqkv = (const float*)d_in[i]; break;
            case 1048576: Wout = (const float*)d_in[i]; break;
            case 1024:    bout = (const float*)d_in[i]; break;
        }
    }
    float* out = (float*)d_out;                  // [2,2048,1024] fp32

    const size_t NE = (size_t)2 * 16 * SEQ * 64; // 4M elems
    __bf16* Qb     = (__bf16*)d_ws;              // 4M
    __bf16* Kb     = Qb + NE;                    // 4M
    __bf16* Vb     = Kb + NE;                    // 4M (dead after transpose_v)
    __bf16* Vtg    = Vb + NE;                    // 4M
    __bf16* Wqkv_t = Vtg + NE;                   // 3M  [3072][1024]
    __bf16* Wout_t = Wqkv_t + (size_t)3072 * 1024; // 1M [1024][1024]
    __bf16* Ao     = Vb;                         // alias: Vb dead by then
    __bf16* SrcBf  = Vtg;                        // alias: Vtg written only later
    // total: 4+4+4+4+3+1 = 20M bf16 = 40MB

    // weight transposes (bf16 convert)
    transpose_f32_to_bf16<<<dim3(3072 / 32, 1024 / 32), 256, 0, stream>>>(
        Wqkv, Wqkv_t, 1024, 3072);
    transpose_f32_to_bf16<<<dim3(1024 / 32, 1024 / 32), 256, 0, stream>>>(
        Wout, Wout_t, 1024, 1024);

    // src -> bf16 (enables gll A-path in GEMM1); lives in Vtg until transpose_v
    convert_f32_to_bf16<<<dim3(4194304 / (256 * 8)), 256, 0, stream>>>(src, SrcBf);

    // GEMM1: src_bf16 @ Wqkv -> scatter Q/K/V
    gemm_kernel<false><<<dim3(3072 / 128, 4096 / 128), 256, 0, stream>>>(
        (const void*)SrcBf, Wqkv_t, bqkv, Qb, Kb, Vb, nullptr, 1024, 3072, 0);

    // V -> V^T (overwrites SrcBf alias; SrcBf dead after GEMM1)
    transpose_v<<<dim3(SEQ / 32, 2, 32), 256, 0, stream>>>(Vb, Vtg);

    // attention
    attn_kernel<<<dim3(32, SEQ / 64), 256, 0, stream>>>(Qb, Kb, Vtg, mask, Ao);

    // GEMM2: Ao(bf16) @ Wout + b -> out (fp32)
    gemm_kernel<false><<<dim3(1024 / 128, 4096 / 128), 256, 0, stream>>>(
        (const void*)Ao, Wout_t, bout, nullptr, nullptr, nullptr, out, 1024, 1024, 1);
}